// Round 6
// baseline (1346.381 us; speedup 1.0000x reference)
//
#include <hip/hip_runtime.h>

typedef unsigned short u16;
typedef unsigned int   u32;

// Problem dims (hardcoded per reference shape_source)
constexpr int Bc  = 4;
constexpr int Nc  = 8192;
constexpr int Hc  = 16;
constexpr int DHc = 64;
constexpr int HD  = Hc * DHc;   // 1024
constexpr int BN  = Bc * Nc;    // 32768

typedef __attribute__((ext_vector_type(8))) short bf16x8;     // 8 bf16 (4 VGPRs)
typedef __attribute__((ext_vector_type(8))) _Float16 f16x8;   // 8 fp16 (4 VGPRs)
typedef __attribute__((ext_vector_type(4))) float f32x4;

struct P8 { float* p[8]; };

// ---------------- bf16 helpers ----------------
__device__ __forceinline__ float bf2f(u32 lo16) {
    return __uint_as_float(lo16 << 16);
}
__device__ __forceinline__ u16 f2bf(float f) {
    u32 u = __float_as_uint(f);
    u += 0x7fffu + ((u >> 16) & 1u);   // round-to-nearest-even
    return (u16)(u >> 16);
}
__device__ __forceinline__ void unpack8(uint4 r, float* d) {
    d[0] = bf2f(r.x & 0xffffu); d[1] = bf2f(r.x >> 16);
    d[2] = bf2f(r.y & 0xffffu); d[3] = bf2f(r.y >> 16);
    d[4] = bf2f(r.z & 0xffffu); d[5] = bf2f(r.z >> 16);
    d[6] = bf2f(r.w & 0xffffu); d[7] = bf2f(r.w >> 16);
}
__device__ __forceinline__ u32 pack2(float a, float b) {
    return (u32)f2bf(a) | ((u32)f2bf(b) << 16);
}

// ---------------- fp16 helpers ----------------
__device__ __forceinline__ u16 f2h(float f) {
    _Float16 h = (_Float16)f;            // RNE
    u16 u; __builtin_memcpy(&u, &h, 2);
    return u;
}
__device__ __forceinline__ u32 pkh2(float a, float b) {
    return (u32)f2h(a) | ((u32)f2h(b) << 16);
}
__device__ __forceinline__ void cvt8h(float4 a, float4 b, uint4& o) {
    o.x = pkh2(a.x, a.y); o.y = pkh2(a.z, a.w);
    o.z = pkh2(b.x, b.y); o.w = pkh2(b.z, b.w);
}

// async global->LDS, 16B per lane
__device__ __forceinline__ void gload_lds16(const void* g, void* lds) {
    __builtin_amdgcn_global_load_lds(
        (const __attribute__((address_space(1))) void*)g,
        (__attribute__((address_space(3))) void*)lds,
        16, 0, 0);
}

// XOR chunk swizzle for [128 rows][32 k] 2-byte-elt tiles (64B rows, 4x16B chunks)
__device__ __forceinline__ int swz_off(int row, int chunk) {
    return row * 64 + (((chunk ^ (row >> 1)) & 3) << 4);
}

// ---------------------------------------------------------------------------
// transpose+split to fp16: W[k][n] f32 -> hiT[n][k] (+ optional loT[n][k])
// ---------------------------------------------------------------------------
__global__ __launch_bounds__(256) void transpose_split_f16(
    const float* __restrict__ W, u16* __restrict__ hiT, u16* __restrict__ loT)
{
    __shared__ float tile[32][33];
    const int bx = blockIdx.x * 32;   // n block
    const int by = blockIdx.y * 32;   // k block
    const int x = threadIdx.x & 31, y4 = threadIdx.x >> 5;
#pragma unroll
    for (int r = 0; r < 4; ++r)
        tile[y4 * 4 + r][x] = W[(size_t)(by + y4 * 4 + r) * 1024 + bx + x];
    __syncthreads();
#pragma unroll
    for (int r = 0; r < 4; ++r) {
        int n = bx + y4 * 4 + r, k = by + x;
        float v = tile[x][y4 * 4 + r];
        _Float16 h = (_Float16)v;
        u16 hu; __builtin_memcpy(&hu, &h, 2);
        hiT[(size_t)n * 1024 + k] = hu;
        if (loT) loT[(size_t)n * 1024 + k] = f2h(v - (float)h);
    }
}

// ---------------------------------------------------------------------------
// Projection GEMM via fp16 MFMA, 1-term, DOUBLE-BUFFERED (T3-min pipeline):
// out_bf16[32768,1024] = (A_f32 @ B) * scale + bias (opt per-row mask)
// per iter: {stage next B (gload_lds) + next A (reg loads)} || {MFMA on cur};
// then cvt+ds_write next A; ONE barrier. Loads overlap compute.
// ---------------------------------------------------------------------------
__global__ __launch_bounds__(256, 4) void proj_gemm_f16(
    const float* __restrict__ A, const u16* __restrict__ BhT,
    const float* __restrict__ bias, const int* __restrict__ maskI,
    u16* __restrict__ outp, float scale)
{
    __shared__ u16 sA[2][128 * 32];
    __shared__ u16 sB[2][128 * 32];

    const int bid = blockIdx.x;
    const int swz = (bid & 7) * 256 + (bid >> 3);
    const int rb  = (swz >> 3) * 128;
    const int cb  = (swz & 7) * 128;
    const int t = threadIdx.x, l = t & 63, w = t >> 6;
    const int wr = (w >> 1) * 64, wc = (w & 1) * 64;

    // A staging (f32 -> fp16, swizzled LDS writes)
    const int ra = t >> 1, ha = t & 1;
    const float* Ap = A + (size_t)(rb + ra) * 1024 + ha * 16;
    const int swA = (ra >> 1) & 3;
    const int oA0 = ra * 64 + (((ha * 2)     ^ swA) << 4);
    const int oA1 = ra * 64 + (((ha * 2 + 1) ^ swA) << 4);

    // B staging via gload_lds (pre-swizzled source)
    const int rB0 = w * 32 + (l >> 2);
    const int rB1 = rB0 + 16;
    const int cB0 = (l & 3) ^ ((rB0 >> 1) & 3);
    const int cB1 = (l & 3) ^ ((rB1 >> 1) & 3);
    const u16* gB0 = BhT + (size_t)(cb + rB0) * 1024 + cB0 * 8;
    const u16* gB1 = BhT + (size_t)(cb + rB1) * 1024 + cB1 * 8;

    f32x4 acc[4][4] = {};
    const int q = l >> 4, r15 = l & 15;

    // ---- prologue: stage tile 0 into buffer 0 ----
    gload_lds16(gB0, &sB[0][w * 1024]);
    gload_lds16(gB1, &sB[0][w * 1024 + 512]);
    {
        float4 f0 = *(const float4*)(Ap);
        float4 f1 = *(const float4*)(Ap + 4);
        float4 f2 = *(const float4*)(Ap + 8);
        float4 f3 = *(const float4*)(Ap + 12);
        uint4 h0, h1;
        cvt8h(f0, f1, h0);
        cvt8h(f2, f3, h1);
        *(uint4*)((char*)sA[0] + oA0) = h0;
        *(uint4*)((char*)sA[0] + oA1) = h1;
    }
    __syncthreads();

    int c = 0;
    for (int k0 = 0; k0 < 1024; k0 += 32) {
        const int nxt = c ^ 1;
        const bool hasNext = (k0 + 32) < 1024;
        float4 f0, f1, f2, f3;
        if (hasNext) {
            gload_lds16(gB0 + k0 + 32, &sB[nxt][w * 1024]);
            gload_lds16(gB1 + k0 + 32, &sB[nxt][w * 1024 + 512]);
            f0 = *(const float4*)(Ap + k0 + 32);
            f1 = *(const float4*)(Ap + k0 + 36);
            f2 = *(const float4*)(Ap + k0 + 40);
            f3 = *(const float4*)(Ap + k0 + 44);
        }

        f16x8 af[4], bfv[4];
#pragma unroll
        for (int i = 0; i < 4; ++i)
            af[i] = *(const f16x8*)((const char*)sA[c] + swz_off(wr + i * 16 + r15, q));
#pragma unroll
        for (int j = 0; j < 4; ++j)
            bfv[j] = *(const f16x8*)((const char*)sB[c] + swz_off(wc + j * 16 + r15, q));
#pragma unroll
        for (int i = 0; i < 4; ++i)
#pragma unroll
            for (int j = 0; j < 4; ++j)
                acc[i][j] = __builtin_amdgcn_mfma_f32_16x16x32_f16(af[i], bfv[j], acc[i][j], 0, 0, 0);

        if (hasNext) {
            uint4 h0, h1;
            cvt8h(f0, f1, h0);
            cvt8h(f2, f3, h1);
            *(uint4*)((char*)sA[nxt] + oA0) = h0;
            *(uint4*)((char*)sA[nxt] + oA1) = h1;
            __syncthreads();
            c = nxt;
        }
    }

    // epilogue: C/D layout col = lane&15, row = (lane>>4)*4 + reg
    const int col0 = cb + wc + r15;
    const int row0 = rb + wr + q * 4;
    float bv4[4];
#pragma unroll
    for (int j = 0; j < 4; ++j) bv4[j] = bias[col0 + j * 16];
#pragma unroll
    for (int i = 0; i < 4; ++i) {
#pragma unroll
        for (int r = 0; r < 4; ++r) {
            int row = row0 + i * 16 + r;
            float mrow = maskI ? (float)maskI[row] : 1.f;
#pragma unroll
            for (int j = 0; j < 4; ++j)
                outp[(size_t)row * 1024 + col0 + j * 16] =
                    f2bf((acc[i][j][r] * scale + bv4[j]) * mrow);
        }
    }
}

// ---------------------------------------------------------------------------
// V projection producing TRANSPOSED output (fp16, double-buffered):
// vT[1024][32768] bf16. A-side = WvT fp16 (gload_lds); B-side = X f32.
// ---------------------------------------------------------------------------
__global__ __launch_bounds__(256, 4) void vproj_gemm_T_f16(
    const float* __restrict__ X, const u16* __restrict__ WhT,
    const float* __restrict__ bias, const int* __restrict__ maskI,
    u16* __restrict__ outT)
{
    __shared__ u16 sW[2][128 * 32];
    __shared__ u16 sX[2][128 * 32];

    const int bid = blockIdx.x;
    const int swz = (bid & 7) * 256 + (bid >> 3);
    const int rbN = (swz & 7) * 128;    // n rows (8 panels)
    const int cbM = (swz >> 3) * 128;   // m cols (256 panels)
    const int t = threadIdx.x, l = t & 63, w = t >> 6;
    const int wrN = (w >> 1) * 64, wcM = (w & 1) * 64;

    const int ra = t >> 1, ha = t & 1;
    const float* Xp = X + (size_t)(cbM + ra) * 1024 + ha * 16;
    const int swA = (ra >> 1) & 3;
    const int oA0 = ra * 64 + (((ha * 2)     ^ swA) << 4);
    const int oA1 = ra * 64 + (((ha * 2 + 1) ^ swA) << 4);

    const int rB0 = w * 32 + (l >> 2);
    const int rB1 = rB0 + 16;
    const int cB0 = (l & 3) ^ ((rB0 >> 1) & 3);
    const int cB1 = (l & 3) ^ ((rB1 >> 1) & 3);
    const u16* gW0 = WhT + (size_t)(rbN + rB0) * 1024 + cB0 * 8;
    const u16* gW1 = WhT + (size_t)(rbN + rB1) * 1024 + cB1 * 8;

    f32x4 acc[4][4] = {};
    const int q = l >> 4, r15 = l & 15;

    gload_lds16(gW0, &sW[0][w * 1024]);
    gload_lds16(gW1, &sW[0][w * 1024 + 512]);
    {
        float4 f0 = *(const float4*)(Xp);
        float4 f1 = *(const float4*)(Xp + 4);
        float4 f2 = *(const float4*)(Xp + 8);
        float4 f3 = *(const float4*)(Xp + 12);
        uint4 h0, h1;
        cvt8h(f0, f1, h0);
        cvt8h(f2, f3, h1);
        *(uint4*)((char*)sX[0] + oA0) = h0;
        *(uint4*)((char*)sX[0] + oA1) = h1;
    }
    __syncthreads();

    int c = 0;
    for (int k0 = 0; k0 < 1024; k0 += 32) {
        const int nxt = c ^ 1;
        const bool hasNext = (k0 + 32) < 1024;
        float4 f0, f1, f2, f3;
        if (hasNext) {
            gload_lds16(gW0 + k0 + 32, &sW[nxt][w * 1024]);
            gload_lds16(gW1 + k0 + 32, &sW[nxt][w * 1024 + 512]);
            f0 = *(const float4*)(Xp + k0 + 32);
            f1 = *(const float4*)(Xp + k0 + 36);
            f2 = *(const float4*)(Xp + k0 + 40);
            f3 = *(const float4*)(Xp + k0 + 44);
        }

        f16x8 aw[4], bx[4];
#pragma unroll
        for (int i = 0; i < 4; ++i)
            aw[i] = *(const f16x8*)((const char*)sW[c] + swz_off(wrN + i * 16 + r15, q));
#pragma unroll
        for (int j = 0; j < 4; ++j)
            bx[j] = *(const f16x8*)((const char*)sX[c] + swz_off(wcM + j * 16 + r15, q));
#pragma unroll
        for (int i = 0; i < 4; ++i)
#pragma unroll
            for (int j = 0; j < 4; ++j)
                acc[i][j] = __builtin_amdgcn_mfma_f32_16x16x32_f16(aw[i], bx[j], acc[i][j], 0, 0, 0);

        if (hasNext) {
            uint4 h0, h1;
            cvt8h(f0, f1, h0);
            cvt8h(f2, f3, h1);
            *(uint4*)((char*)sX[nxt] + oA0) = h0;
            *(uint4*)((char*)sX[nxt] + oA1) = h1;
            __syncthreads();
            c = nxt;
        }
    }

    // C/D: row (n) = rbN + wrN + i*16 + q*4 + r; col (m) = cbM + wcM + j*16 + r15
#pragma unroll
    for (int i = 0; i < 4; ++i)
#pragma unroll
        for (int r = 0; r < 4; ++r) {
            int n = rbN + wrN + i * 16 + q * 4 + r;
            float bn = bias[n];
#pragma unroll
            for (int j = 0; j < 4; ++j) {
                int mcol = cbM + wcM + j * 16 + r15;
                float mv = (float)maskI[mcol];
                outT[(size_t)n * 32768 + mcol] = f2bf((acc[i][j][r] + bn) * mv);
            }
        }
}

// ---------------------------------------------------------------------------
// Output GEMM via fp16 MFMA (2-term, double-buffered): f32 out = pre @ Wo + bo
// ---------------------------------------------------------------------------
__global__ __launch_bounds__(256, 3) void out_gemm_f16(
    const u16* __restrict__ A, const u16* __restrict__ BhiT,
    const u16* __restrict__ BloT, const float* __restrict__ bias,
    float* __restrict__ outp)
{
    __shared__ u16 sA[2][128 * 32];
    __shared__ u16 sBhi[2][128 * 32], sBlo[2][128 * 32];

    const int bid = blockIdx.x;
    const int swz = (bid & 7) * 256 + (bid >> 3);
    const int rb  = (swz >> 3) * 128;
    const int cb  = (swz & 7) * 128;
    const int t = threadIdx.x, l = t & 63, w = t >> 6;
    const int wr = (w >> 1) * 64, wc = (w & 1) * 64;

    const int rS0 = w * 32 + (l >> 2);
    const int rS1 = rS0 + 16;
    const int cS0 = (l & 3) ^ ((rS0 >> 1) & 3);
    const int cS1 = (l & 3) ^ ((rS1 >> 1) & 3);
    const u16* gA0  = A    + (size_t)(rb + rS0) * 1024 + cS0 * 8;
    const u16* gA1  = A    + (size_t)(rb + rS1) * 1024 + cS1 * 8;
    const u16* gBh0 = BhiT + (size_t)(cb + rS0) * 1024 + cS0 * 8;
    const u16* gBh1 = BhiT + (size_t)(cb + rS1) * 1024 + cS1 * 8;
    const u16* gBl0 = BloT + (size_t)(cb + rS0) * 1024 + cS0 * 8;
    const u16* gBl1 = BloT + (size_t)(cb + rS1) * 1024 + cS1 * 8;

    f32x4 acc[4][4] = {};
    const int q = l >> 4, r15 = l & 15;

    // prologue: stage tile 0 into buffer 0
    gload_lds16(gA0,  &sA[0][w * 1024]);
    gload_lds16(gA1,  &sA[0][w * 1024 + 512]);
    gload_lds16(gBh0, &sBhi[0][w * 1024]);
    gload_lds16(gBh1, &sBhi[0][w * 1024 + 512]);
    gload_lds16(gBl0, &sBlo[0][w * 1024]);
    gload_lds16(gBl1, &sBlo[0][w * 1024 + 512]);
    __syncthreads();

    int c = 0;
    for (int k0 = 0; k0 < 1024; k0 += 32) {
        const int nxt = c ^ 1;
        const bool hasNext = (k0 + 32) < 1024;
        if (hasNext) {
            gload_lds16(gA0  + k0 + 32, &sA[nxt][w * 1024]);
            gload_lds16(gA1  + k0 + 32, &sA[nxt][w * 1024 + 512]);
            gload_lds16(gBh0 + k0 + 32, &sBhi[nxt][w * 1024]);
            gload_lds16(gBh1 + k0 + 32, &sBhi[nxt][w * 1024 + 512]);
            gload_lds16(gBl0 + k0 + 32, &sBlo[nxt][w * 1024]);
            gload_lds16(gBl1 + k0 + 32, &sBlo[nxt][w * 1024 + 512]);
        }

        f16x8 af[4], bh[4], bl[4];
#pragma unroll
        for (int i = 0; i < 4; ++i)
            af[i] = *(const f16x8*)((const char*)sA[c] + swz_off(wr + i * 16 + r15, q));
#pragma unroll
        for (int j = 0; j < 4; ++j) {
            int off = swz_off(wc + j * 16 + r15, q);
            bh[j] = *(const f16x8*)((const char*)sBhi[c] + off);
            bl[j] = *(const f16x8*)((const char*)sBlo[c] + off);
        }
#pragma unroll
        for (int i = 0; i < 4; ++i)
#pragma unroll
            for (int j = 0; j < 4; ++j) {
                acc[i][j] = __builtin_amdgcn_mfma_f32_16x16x32_f16(af[i], bh[j], acc[i][j], 0, 0, 0);
                acc[i][j] = __builtin_amdgcn_mfma_f32_16x16x32_f16(af[i], bl[j], acc[i][j], 0, 0, 0);
            }

        if (hasNext) {
            __syncthreads();
            c = nxt;
        }
    }

    const int col0 = cb + wc + r15;
    const int row0 = rb + wr + q * 4;
    float bv4[4];
#pragma unroll
    for (int j = 0; j < 4; ++j) bv4[j] = bias[col0 + j * 16];
#pragma unroll
    for (int i = 0; i < 4; ++i)
#pragma unroll
        for (int r = 0; r < 4; ++r) {
            int row = row0 + i * 16 + r;
#pragma unroll
            for (int j = 0; j < 4; ++j)
                outp[(size_t)row * 1024 + col0 + j * 16] = acc[i][j][r] + bv4[j];
        }
}

// ---------------------------------------------------------------------------
__global__ void mask_to_float(const int* __restrict__ mi, float* __restrict__ mo)
{
    int i = blockIdx.x * 256 + threadIdx.x;
    if (i < BN) mo[i] = (float)mi[i];
}

__global__ void sentinel_fill(float* __restrict__ o, int n)
{
    int i = blockIdx.x * 256 + threadIdx.x;
    if (i < n) o[i] = 12345.0f;
}

// ---------------------------------------------------------------------------
// avg-pool-2 along seq: q,k row-major (y 0,1); vT transposed (y 2); mask (y 3)
// ---------------------------------------------------------------------------
__global__ __launch_bounds__(256) void pool_level(
    const u16* __restrict__ qi, u16* __restrict__ qo,
    const u16* __restrict__ ki, u16* __restrict__ ko,
    const u16* __restrict__ vi, u16* __restrict__ vo,
    const float* __restrict__ mi, float* __restrict__ mo, int nRows)
{
    int idx = blockIdx.x * 256 + threadIdx.x;
    int y   = blockIdx.y;
    if (y == 3) {
        if (idx < nRows) mo[idx] = 0.5f * (mi[2 * idx] + mi[2 * idx + 1]);
        return;
    }
    if (y == 2) {
        int ns8 = nRows >> 3;
        int sh = 31 - __clz(ns8);
        int d = idx >> sh, c = idx & (ns8 - 1);
        size_t inb = (size_t)d * (nRows * 2) + c * 16;
        uint4 a = *(const uint4*)(vi + inb);
        uint4 b = *(const uint4*)(vi + inb + 8);
        float fa[8], fb[8];
        unpack8(a, fa); unpack8(b, fb);
        uint4 o;
        o.x = pack2(0.5f * (fa[0] + fa[1]), 0.5f * (fa[2] + fa[3]));
        o.y = pack2(0.5f * (fa[4] + fa[5]), 0.5f * (fa[6] + fa[7]));
        o.z = pack2(0.5f * (fb[0] + fb[1]), 0.5f * (fb[2] + fb[3]));
        o.w = pack2(0.5f * (fb[4] + fb[5]), 0.5f * (fb[6] + fb[7]));
        *(uint4*)(vo + (size_t)d * nRows + c * 8) = o;
        return;
    }
    const u16* in  = (y == 0) ? qi : ki;
    u16*       out = (y == 0) ? qo : ko;
    int r = idx >> 7, c8 = idx & 127;
    uint4 a = *(const uint4*)(in + (size_t)(2 * r) * 1024 + c8 * 8);
    uint4 b = *(const uint4*)(in + (size_t)(2 * r + 1) * 1024 + c8 * 8);
    float fa[8], fb[8];
    unpack8(a, fa); unpack8(b, fb);
    uint4 o;
    o.x = pack2(0.5f * (fa[0] + fb[0]), 0.5f * (fa[1] + fb[1]));
    o.y = pack2(0.5f * (fa[2] + fb[2]), 0.5f * (fa[3] + fb[3]));
    o.z = pack2(0.5f * (fa[4] + fb[4]), 0.5f * (fa[5] + fb[5]));
    o.w = pack2(0.5f * (fa[6] + fb[6]), 0.5f * (fa[7] + fb[7]));
    *(uint4*)(out + (size_t)r * 1024 + c8 * 8) = o;
}

// ===========================================================================
// Shared body for the MFMA attention level. WRITE_MODE:
//   0 = pyramid: write num/den at LEVEL resolution (no RMW)
//   1 = legacy:  accumulate into full-res num/den with repeat 2^lvl
// ===========================================================================
template <int WRITE_MODE>
__device__ __forceinline__ void attn_level_body(
    const u16* __restrict__ qg, const u16* __restrict__ kg,
    const u16* __restrict__ vTg, const float* __restrict__ m,
    const float* __restrict__ rpbL,
    float* __restrict__ num, float* __restrict__ den, int nl, int lvl)
{
    __shared__ u16 qs[32 * 64];
    __shared__ u16 ks_w2[2 * 32 * 104];
    __shared__ u16 vTs[64 * 96];
    __shared__ float rps[128];
    __shared__ float mwS[96];
    __shared__ float denS[64];

    const int t   = threadIdx.x;
    const int blk = blockIdx.x, h = blockIdx.y, b = blockIdx.z;
    const size_t baseRow = (size_t)b * nl + blk * 32;
    const int wbase = blk * 32 - 32;
    const int vStr = Bc * nl;

    {
        int r = t >> 3, c = t & 7;
        uint4 raw = *(const uint4*)(qg + (baseRow + r) * 1024 + h * 64 + c * 8);
        *(uint4*)&qs[r * 64 + ((c ^ (r & 7)) * 8)] = raw;
    }
#pragma unroll
    for (int it = 0; it < 3; ++it) {
        int f = t + 256 * it;
        int r = f >> 3, c = f & 7;
        int wp = wbase + r;
        uint4 raw = make_uint4(0u, 0u, 0u, 0u);
        if (wp >= 0 && wp < nl)
            raw = *(const uint4*)(kg + ((size_t)b * nl + wp) * 1024 + h * 64 + c * 8);
        *(uint4*)&ks_w2[r * 64 + ((c ^ (r & 7)) * 8)] = raw;
    }
    {
        int d = t >> 2, c3 = t & 3;
        const u16* vrow = vTg + (size_t)(h * 64 + d) * vStr + (size_t)b * nl;
#pragma unroll
        for (int o = 0; o < 3; ++o) {
            int s8 = c3 * 24 + o * 8;
            int wp8 = wbase + s8;
            uint4 raw = make_uint4(0u, 0u, 0u, 0u);
            if (wp8 >= 0 && wp8 < nl)
                raw = *(const uint4*)(vrow + wp8);
            *(uint4*)&vTs[d * 96 + s8] = raw;
        }
    }
    if (t < 96) {
        int wp = wbase + t;
        mwS[t] = (wp >= 0 && wp < nl) ? m[b * nl + wp] : 0.f;
    }
    if (t < 127) rps[t] = rpbL[h * 127 + t];
    __syncthreads();

    const int l  = t & 63, w = t >> 6;
    const int fr = l & 15, fg = l >> 4;
    const int mi  = w >> 1;
    const int njb = (w & 1) * 3;

    f32x4 lg[3] = {};
    {
        bf16x8 aq[2];
#pragma unroll
        for (int ks = 0; ks < 2; ++ks) {
            int row = mi * 16 + fr;
            aq[ks] = *(const bf16x8*)&qs[row * 64 + (((ks * 4 + fg) ^ (row & 7)) * 8)];
        }
#pragma unroll
        for (int nj = 0; nj < 3; ++nj) {
            int row = (njb + nj) * 16 + fr;
#pragma unroll
            for (int ks = 0; ks < 2; ++ks) {
                bf16x8 bk = *(const bf16x8*)&ks_w2[row * 64 + (((ks * 4 + fg) ^ (row & 7)) * 8)];
                lg[nj] = __builtin_amdgcn_mfma_f32_16x16x32_bf16(aq[ks], bk, lg[nj], 0, 0, 0);
            }
        }
    }
    __syncthreads();

    float sum_r[4] = {0.f, 0.f, 0.f, 0.f};
#pragma unroll
    for (int nj = 0; nj < 3; ++nj) {
        int j = (njb + nj) * 16 + fr;
        float mj = mwS[j];
#pragma unroll
        for (int r = 0; r < 4; ++r) {
            int i = mi * 16 + fg * 4 + r;
            float wv = __expf(lg[nj][r] + rps[j - i + 31]) * mj;
            if (lvl > 0) {
                int bj = j >> 5, pl = j & 31;
                bool inv = (bj == 1) ||
                           (bj == 0 && i < 16 && pl >= 16) ||
                           (bj == 2 && i >= 16 && pl < 16);
                if (inv) wv = 0.f;
            }
            sum_r[r] += wv;
            u32 uw = __float_as_uint(wv);
            float lo = wv - __uint_as_float(uw & 0xffff0000u);
            ks_w2[i * 104 + j]        = (u16)(uw >> 16);
            ks_w2[3328 + i * 104 + j] = (u16)(__float_as_uint(lo) >> 16);
        }
    }
#pragma unroll
    for (int r = 0; r < 4; ++r) {
        sum_r[r] += __shfl_xor(sum_r[r], 1);
        sum_r[r] += __shfl_xor(sum_r[r], 2);
        sum_r[r] += __shfl_xor(sum_r[r], 4);
        sum_r[r] += __shfl_xor(sum_r[r], 8);
    }
    if (fr == 0) {
#pragma unroll
        for (int r = 0; r < 4; ++r)
            denS[(w & 1) * 32 + mi * 16 + fg * 4 + r] = sum_r[r];
    }
    __syncthreads();

    const int ndb = (w & 1) * 2;
    f32x4 acc0 = {}, acc1 = {};
#pragma unroll
    for (int ks = 0; ks < 3; ++ks) {
        int arow = mi * 16 + fr;
        bf16x8 ah = *(const bf16x8*)&ks_w2[arow * 104 + ks * 32 + fg * 8];
        bf16x8 al = *(const bf16x8*)&ks_w2[3328 + arow * 104 + ks * 32 + fg * 8];
        int d0 = ndb * 16 + fr;
        bf16x8 bv0 = *(const bf16x8*)&vTs[d0 * 96 + ks * 32 + fg * 8];
        bf16x8 bv1 = *(const bf16x8*)&vTs[(d0 + 16) * 96 + ks * 32 + fg * 8];
        acc0 = __builtin_amdgcn_mfma_f32_16x16x32_bf16(ah, bv0, acc0, 0, 0, 0);
        acc0 = __builtin_amdgcn_mfma_f32_16x16x32_bf16(al, bv0, acc0, 0, 0, 0);
        acc1 = __builtin_amdgcn_mfma_f32_16x16x32_bf16(ah, bv1, acc1, 0, 0, 0);
        acc1 = __builtin_amdgcn_mfma_f32_16x16x32_bf16(al, bv1, acc1, 0, 0, 0);
    }

    const int i0 = mi * 16 + fg * 4;
    const int d0 = ndb * 16 + fr;
    if (WRITE_MODE == 0) {
#pragma unroll
        for (int r = 0; r < 4; ++r) {
            int cn = blk * 32 + i0 + r;
            size_t base = ((size_t)b * nl + cn) * 1024 + h * 64;
            num[base + d0]      = acc0[r];
            num[base + d0 + 16] = acc1[r];
        }
        if (t < 32) {
            float s = denS[t] + denS[32 + t];
            den[((size_t)b * nl + blk * 32 + t) * 16 + h] = s;
        }
    } else {
        const int rr = 1 << lvl;
#pragma unroll
        for (int r = 0; r < 4; ++r) {
            int cn = blk * 32 + i0 + r;
            size_t base = ((size_t)b * Nc + (size_t)cn * rr) * 1024 + h * 64;
            if (lvl == 0) {
                num[base + d0]      = acc0[r];
                num[base + d0 + 16] = acc1[r];
            } else {
                for (int rep = 0; rep < rr; ++rep) {
                    num[base + (size_t)rep * 1024 + d0]      += acc0[r];
                    num[base + (size_t)rep * 1024 + d0 + 16] += acc1[r];
                }
            }
        }
        if (t < 32) {
            float s = denS[t] + denS[32 + t];
            int cn = blk * 32 + t;
            size_t db = ((size_t)b * Nc + (size_t)cn * rr) * 16 + h;
            if (lvl == 0) {
                den[db] = s;
            } else {
                for (int rep = 0; rep < rr; ++rep) den[db + (size_t)rep * 16] += s;
            }
        }
    }
}

__global__ __launch_bounds__(256) void attn_level_pyr(
    const u16* __restrict__ qg, const u16* __restrict__ kg,
    const u16* __restrict__ vTg, const float* __restrict__ m,
    const float* __restrict__ rpbL,
    float* __restrict__ numL, float* __restrict__ denL, int nl, int lvl)
{
    attn_level_body<0>(qg, kg, vTg, m, rpbL, numL, denL, nl, lvl);
}

__global__ __launch_bounds__(256) void attn_level_rmw(
    const u16* __restrict__ qg, const u16* __restrict__ kg,
    const u16* __restrict__ vTg, const float* __restrict__ m,
    const float* __restrict__ rpbL,
    float* __restrict__ num, float* __restrict__ den, int nl, int lvl)
{
    attn_level_body<1>(qg, kg, vTg, m, rpbL, num, den, nl, lvl);
}

// ---------------------------------------------------------------------------
// combine (legacy): pre_fp16 = num / (den + 1e-9) * qmask
// ---------------------------------------------------------------------------
__global__ __launch_bounds__(256) void combine_kernel(
    const float* __restrict__ num, const float* __restrict__ den,
    const int* __restrict__ qmask, u16* __restrict__ pre)
{
    int idx = blockIdx.x * 256 + threadIdx.x;
    int row = idx >> 8, c4 = idx & 255;
    int h = c4 >> 4;
    float4 ns = *(const float4*)&num[(size_t)row * 1024 + c4 * 4];
    float f = (float)qmask[row] / (den[(size_t)row * 16 + h] + 1e-9f);
    ushort4 o;
    o.x = f2h(ns.x * f); o.y = f2h(ns.y * f);
    o.z = f2h(ns.z * f); o.w = f2h(ns.w * f);
    *(ushort4*)(pre + (size_t)row * 1024 + c4 * 4) = o;
}

// ---------------------------------------------------------------------------
// combine (pyramid): gather 8 levels, sum f32 in level order; pre as fp16.
// ---------------------------------------------------------------------------
__global__ __launch_bounds__(256) void combine_pyr(
    P8 nums, P8 dens, const int* __restrict__ qmask, u16* __restrict__ pre)
{
    int idx = blockIdx.x * 256 + threadIdx.x;
    int row = idx >> 8, c4 = idx & 255;
    int h = c4 >> 4;
    int b = row >> 13, s = row & (Nc - 1);
    float4 acc = make_float4(0.f, 0.f, 0.f, 0.f);
    float dt = 0.f;
#pragma unroll
    for (int l = 0; l < 8; ++l) {
        int rl = (b << (13 - l)) + (s >> l);
        const float4 nv = *(const float4*)&nums.p[l][(size_t)rl * 1024 + c4 * 4];
        acc.x += nv.x; acc.y += nv.y; acc.z += nv.z; acc.w += nv.w;
        dt += dens.p[l][(size_t)rl * 16 + h];
    }
    float f = (float)qmask[row] / (dt + 1e-9f);
    ushort4 o;
    o.x = f2h(acc.x * f); o.y = f2h(acc.y * f);
    o.z = f2h(acc.z * f); o.w = f2h(acc.w * f);
    *(ushort4*)(pre + (size_t)row * 1024 + c4 * 4) = o;
}

// ---------------------------------------------------------------------------
extern "C" void kernel_launch(void* const* d_in, const int* in_sizes, int n_in,
                              void* d_out, int out_size, void* d_ws, size_t ws_size,
                              hipStream_t stream)
{
    const float* Xq    = (const float*)d_in[0];
    const float* Xkv   = (const float*)d_in[1];
    const int*   qmask = (const int*)d_in[2];
    const int*   kmask = (const int*)d_in[3];
    const float* Wq    = (const float*)d_in[4];
    const float* bq    = (const float*)d_in[5];
    const float* Wk    = (const float*)d_in[6];
    const float* bk    = (const float*)d_in[7];
    const float* Wv    = (const float*)d_in[8];
    const float* bv    = (const float*)d_in[9];
    const float* Wo    = (const float*)d_in[10];
    const float* bo    = (const float*)d_in[11];
    const float* rpb   = (const float*)d_in[12];

    const size_t szA = (size_t)BN * HD * 2;   // 67,108,864
    const size_t szB = szA / 2;
    const size_t base_need = 3 * (szA + szB) + (size_t)BN * 6;

    size_t denPyrSz = 0, numPyrSz = 0;
    for (int l = 0; l < 8; ++l) denPyrSz += ((size_t)(BN >> l)) * 16 * 4;
    for (int l = 1; l < 8; ++l) numPyrSz += ((size_t)(BN >> l)) * 1024 * 4;
    const size_t needed_old = base_need + (size_t)BN * 16 * 4;
    const size_t needed_pyr = base_need + denPyrSz + numPyrSz;

    const bool usePyr = (ws_size >= needed_pyr);
    if (!usePyr && ws_size < needed_old) {
        sentinel_fill<<<(out_size + 255) / 256, 256, 0, stream>>>((float*)d_out, out_size);
        return;
    }

    char* p = (char*)d_ws;
    u16* qA = (u16*)p; p += szA;
    u16* qB = (u16*)p; p += szB;
    u16* kA = (u16*)p; p += szA;
    u16* kB = (u16*)p; p += szB;
    u16* vA = (u16*)p; p += szA;     // vT pyramid (transposed)
    u16* vB = (u16*)p; p += szB;
    float* mA  = (float*)p; p += (size_t)BN * 4;
    float* mB  = (float*)p; p += (size_t)BN * 2;

    P8 numP, denP;
    float* denLegacy = nullptr;
    if (usePyr) {
        for (int l = 0; l < 8; ++l) { denP.p[l] = (float*)p; p += ((size_t)(BN >> l)) * 16 * 4; }
        numP.p[0] = (float*)d_out;
        for (int l = 1; l < 8; ++l) { numP.p[l] = (float*)p; p += ((size_t)(BN >> l)) * 1024 * 4; }
    } else {
        denLegacy = (float*)p;
    }
    float* num = (float*)d_out;

    u16* WsHi0 = qB;
    u16* WsLo0 = qB + 1 * 1048576;
    u16* WsHi1 = qB + 2 * 1048576;
    u16* WsHi2 = qB + 4 * 1048576;

    dim3 tsg(32, 32);
    transpose_split_f16<<<tsg, 256, 0, stream>>>(Wq, WsHi0, nullptr);
    transpose_split_f16<<<tsg, 256, 0, stream>>>(Wk, WsHi1, nullptr);
    transpose_split_f16<<<tsg, 256, 0, stream>>>(Wv, WsHi2, nullptr);

    proj_gemm_f16 <<<2048, 256, 0, stream>>>(Xq,  WsHi0, bq, nullptr, qA, 0.125f);
    proj_gemm_f16 <<<2048, 256, 0, stream>>>(Xkv, WsHi1, bk, nullptr, kA, 1.f);
    vproj_gemm_T_f16<<<2048, 256, 0, stream>>>(Xkv, WsHi2, bv, kmask, vA);
    mask_to_float<<<BN / 256, 256, 0, stream>>>(kmask, mA);

    u16* qc = qA; u16* kc = kA; u16* vc = vA; float* mc = mA;
    u16* qn = qB; u16* kn = kB; u16* vn = vB; float* mn = mB;
    for (int lvl = 0; lvl < 8; ++lvl) {
        int nl = Nc >> lvl, nb = nl / 32;
        if (usePyr) {
            attn_level_pyr<<<dim3(nb, 16, 4), 256, 0, stream>>>(
                qc, kc, vc, mc, rpb + (size_t)lvl * Hc * 127,
                numP.p[lvl], denP.p[lvl], nl, lvl);
        } else {
            attn_level_rmw<<<dim3(nb, 16, 4), 256, 0, stream>>>(
                qc, kc, vc, mc, rpb + (size_t)lvl * Hc * 127,
                num, denLegacy, nl, lvl);
        }
        if (lvl < 7) {
            int nRows = Bc * (nl / 2);
            pool_level<<<dim3(nRows / 2, 4), 256, 0, stream>>>(
                qc, qn, kc, kn, vc, vn, mc, mn, nRows);
            u16* tp;
            tp = qc; qc = qn; qn = tp;
            tp = kc; kc = kn; kn = tp;
            tp = vc; vc = vn; vn = tp;
            float* tf = mc; mc = mn; mn = tf;
        }
    }

    if (usePyr) {
        combine_pyr<<<BN, 256, 0, stream>>>(numP, denP, qmask, qA);
    } else {
        combine_kernel<<<BN, 256, 0, stream>>>(num, denLegacy, qmask, qA);
    }
    // Wo hi/lo fp16 split into qB (dead after last pool; slots 0 and 1)
    u16* WoHi = qB;
    u16* WoLo = qB + 1 * 1048576;
    transpose_split_f16<<<tsg, 256, 0, stream>>>(Wo, WoHi, WoLo);
    out_gemm_f16<<<2048, 256, 0, stream>>>(qA, WoHi, WoLo, bo, (float*)d_out);
}

// Round 7
// 1219.673 us; speedup vs baseline: 1.1039x; 1.1039x over previous
//
#include <hip/hip_runtime.h>

typedef unsigned short u16;
typedef unsigned int   u32;

// Problem dims (hardcoded per reference shape_source)
constexpr int Bc  = 4;
constexpr int Nc  = 8192;
constexpr int Hc  = 16;
constexpr int DHc = 64;
constexpr int HD  = Hc * DHc;   // 1024
constexpr int BN  = Bc * Nc;    // 32768

typedef __attribute__((ext_vector_type(8))) short bf16x8;     // 8 bf16 (4 VGPRs)
typedef __attribute__((ext_vector_type(8))) _Float16 f16x8;   // 8 fp16 (4 VGPRs)
typedef __attribute__((ext_vector_type(4))) float f32x4;

struct P8 { float* p[8]; };

// ---------------- bf16 helpers ----------------
__device__ __forceinline__ float bf2f(u32 lo16) {
    return __uint_as_float(lo16 << 16);
}
__device__ __forceinline__ u16 f2bf(float f) {
    u32 u = __float_as_uint(f);
    u += 0x7fffu + ((u >> 16) & 1u);   // round-to-nearest-even
    return (u16)(u >> 16);
}
__device__ __forceinline__ void unpack8(uint4 r, float* d) {
    d[0] = bf2f(r.x & 0xffffu); d[1] = bf2f(r.x >> 16);
    d[2] = bf2f(r.y & 0xffffu); d[3] = bf2f(r.y >> 16);
    d[4] = bf2f(r.z & 0xffffu); d[5] = bf2f(r.z >> 16);
    d[6] = bf2f(r.w & 0xffffu); d[7] = bf2f(r.w >> 16);
}
__device__ __forceinline__ u32 pack2(float a, float b) {
    return (u32)f2bf(a) | ((u32)f2bf(b) << 16);
}

// ---------------- fp16 helpers ----------------
__device__ __forceinline__ u16 f2h(float f) {
    _Float16 h = (_Float16)f;            // RNE
    u16 u; __builtin_memcpy(&u, &h, 2);
    return u;
}
__device__ __forceinline__ u32 pkh2(float a, float b) {
    return (u32)f2h(a) | ((u32)f2h(b) << 16);
}
__device__ __forceinline__ void cvt8h(float4 a, float4 b, uint4& o) {
    o.x = pkh2(a.x, a.y); o.y = pkh2(a.z, a.w);
    o.z = pkh2(b.x, b.y); o.w = pkh2(b.z, b.w);
}

// async global->LDS, 16B per lane (dest = wave-uniform base + lane*16)
__device__ __forceinline__ void gload_lds16(const void* g, void* lds) {
    __builtin_amdgcn_global_load_lds(
        (const __attribute__((address_space(1))) void*)g,
        (__attribute__((address_space(3))) void*)lds,
        16, 0, 0);
}

// XOR chunk swizzle for [128 rows][32 k] 2-byte-elt tiles (64B rows, 4x16B chunks)
__device__ __forceinline__ int swz_off(int row, int chunk) {
    return row * 64 + (((chunk ^ (row >> 1)) & 3) << 4);
}

// ---------------------------------------------------------------------------
// transpose+split to fp16: W[k][n] f32 -> hiT[n][k] (+ optional loT[n][k])
// ---------------------------------------------------------------------------
__global__ __launch_bounds__(256) void transpose_split_f16(
    const float* __restrict__ W, u16* __restrict__ hiT, u16* __restrict__ loT)
{
    __shared__ float tile[32][33];
    const int bx = blockIdx.x * 32;   // n block
    const int by = blockIdx.y * 32;   // k block
    const int x = threadIdx.x & 31, y4 = threadIdx.x >> 5;
#pragma unroll
    for (int r = 0; r < 4; ++r)
        tile[y4 * 4 + r][x] = W[(size_t)(by + y4 * 4 + r) * 1024 + bx + x];
    __syncthreads();
#pragma unroll
    for (int r = 0; r < 4; ++r) {
        int n = bx + y4 * 4 + r, k = by + x;
        float v = tile[x][y4 * 4 + r];
        _Float16 h = (_Float16)v;
        u16 hu; __builtin_memcpy(&hu, &h, 2);
        hiT[(size_t)n * 1024 + k] = hu;
        if (loT) loT[(size_t)n * 1024 + k] = f2h(v - (float)h);
    }
}

// ---------------------------------------------------------------------------
// Projection GEMM via fp16 MFMA, 1-term (round-5 single-buffer structure):
// out_bf16[32768,1024] = (A_f32 @ B) * scale + bias (opt per-row mask)
// ---------------------------------------------------------------------------
__global__ __launch_bounds__(256, 2) void proj_gemm_f16(
    const float* __restrict__ A, const u16* __restrict__ BhT,
    const float* __restrict__ bias, const int* __restrict__ maskI,
    u16* __restrict__ outp, float scale)
{
    __shared__ u16 sA[128 * 32];
    __shared__ u16 sB[128 * 32];

    const int bid = blockIdx.x;
    const int swz = (bid & 7) * 256 + (bid >> 3);
    const int rb  = (swz >> 3) * 128;
    const int cb  = (swz & 7) * 128;
    const int t = threadIdx.x, l = t & 63, w = t >> 6;
    const int wr = (w >> 1) * 64, wc = (w & 1) * 64;

    // A staging (f32 -> fp16, swizzled LDS writes)
    const int ra = t >> 1, ha = t & 1;
    const float* Ap = A + (size_t)(rb + ra) * 1024 + ha * 16;
    const int swA = (ra >> 1) & 3;
    const int oA0 = ra * 64 + (((ha * 2)     ^ swA) << 4);
    const int oA1 = ra * 64 + (((ha * 2 + 1) ^ swA) << 4);

    // B staging via gload_lds (pre-swizzled source)
    const int rB0 = w * 32 + (l >> 2);
    const int rB1 = rB0 + 16;
    const int cB0 = (l & 3) ^ ((rB0 >> 1) & 3);
    const int cB1 = (l & 3) ^ ((rB1 >> 1) & 3);
    const u16* gB0 = BhT + (size_t)(cb + rB0) * 1024 + cB0 * 8;
    const u16* gB1 = BhT + (size_t)(cb + rB1) * 1024 + cB1 * 8;
    u16* ldsB0 = &sB[w * 1024];
    u16* ldsB1 = &sB[w * 1024 + 512];

    f32x4 acc[4][4] = {};
    const int q = l >> 4, r15 = l & 15;

    for (int k0 = 0; k0 < 1024; k0 += 32) {
        gload_lds16(gB0 + k0, ldsB0);
        gload_lds16(gB1 + k0, ldsB1);

        float4 f0 = *(const float4*)(Ap + k0);
        float4 f1 = *(const float4*)(Ap + k0 + 4);
        float4 f2 = *(const float4*)(Ap + k0 + 8);
        float4 f3 = *(const float4*)(Ap + k0 + 12);
        uint4 h0, h1;
        cvt8h(f0, f1, h0);
        cvt8h(f2, f3, h1);
        *(uint4*)((char*)sA + oA0) = h0;
        *(uint4*)((char*)sA + oA1) = h1;
        __syncthreads();

        f16x8 af[4], bfv[4];
#pragma unroll
        for (int i = 0; i < 4; ++i)
            af[i] = *(const f16x8*)((const char*)sA + swz_off(wr + i * 16 + r15, q));
#pragma unroll
        for (int j = 0; j < 4; ++j)
            bfv[j] = *(const f16x8*)((const char*)sB + swz_off(wc + j * 16 + r15, q));
#pragma unroll
        for (int i = 0; i < 4; ++i)
#pragma unroll
            for (int j = 0; j < 4; ++j)
                acc[i][j] = __builtin_amdgcn_mfma_f32_16x16x32_f16(af[i], bfv[j], acc[i][j], 0, 0, 0);
        __syncthreads();
    }

    // epilogue: C/D layout col = lane&15, row = (lane>>4)*4 + reg
    const int col0 = cb + wc + r15;
    const int row0 = rb + wr + q * 4;
    float bv4[4];
#pragma unroll
    for (int j = 0; j < 4; ++j) bv4[j] = bias[col0 + j * 16];
#pragma unroll
    for (int i = 0; i < 4; ++i) {
#pragma unroll
        for (int r = 0; r < 4; ++r) {
            int row = row0 + i * 16 + r;
            float mrow = maskI ? (float)maskI[row] : 1.f;
#pragma unroll
            for (int j = 0; j < 4; ++j)
                outp[(size_t)row * 1024 + col0 + j * 16] =
                    f2bf((acc[i][j][r] * scale + bv4[j]) * mrow);
        }
    }
}

// ---------------------------------------------------------------------------
// V projection producing TRANSPOSED output (fp16, round-5 structure):
// vT[1024][32768] bf16.
// ---------------------------------------------------------------------------
__global__ __launch_bounds__(256, 2) void vproj_gemm_T_f16(
    const float* __restrict__ X, const u16* __restrict__ WhT,
    const float* __restrict__ bias, const int* __restrict__ maskI,
    u16* __restrict__ outT)
{
    __shared__ u16 sW[128 * 32];
    __shared__ u16 sX[128 * 32];

    const int bid = blockIdx.x;
    const int swz = (bid & 7) * 256 + (bid >> 3);
    const int rbN = (swz & 7) * 128;    // n rows (8 panels)
    const int cbM = (swz >> 3) * 128;   // m cols (256 panels)
    const int t = threadIdx.x, l = t & 63, w = t >> 6;
    const int wrN = (w >> 1) * 64, wcM = (w & 1) * 64;

    const int ra = t >> 1, ha = t & 1;
    const float* Xp = X + (size_t)(cbM + ra) * 1024 + ha * 16;
    const int swA = (ra >> 1) & 3;
    const int oA0 = ra * 64 + (((ha * 2)     ^ swA) << 4);
    const int oA1 = ra * 64 + (((ha * 2 + 1) ^ swA) << 4);

    const int rB0 = w * 32 + (l >> 2);
    const int rB1 = rB0 + 16;
    const int cB0 = (l & 3) ^ ((rB0 >> 1) & 3);
    const int cB1 = (l & 3) ^ ((rB1 >> 1) & 3);
    const u16* gW0 = WhT + (size_t)(rbN + rB0) * 1024 + cB0 * 8;
    const u16* gW1 = WhT + (size_t)(rbN + rB1) * 1024 + cB1 * 8;
    u16* ldsW0 = &sW[w * 1024];
    u16* ldsW1 = &sW[w * 1024 + 512];

    f32x4 acc[4][4] = {};
    const int q = l >> 4, r15 = l & 15;

    for (int k0 = 0; k0 < 1024; k0 += 32) {
        gload_lds16(gW0 + k0, ldsW0);
        gload_lds16(gW1 + k0, ldsW1);

        float4 f0 = *(const float4*)(Xp + k0);
        float4 f1 = *(const float4*)(Xp + k0 + 4);
        float4 f2 = *(const float4*)(Xp + k0 + 8);
        float4 f3 = *(const float4*)(Xp + k0 + 12);
        uint4 h0, h1;
        cvt8h(f0, f1, h0);
        cvt8h(f2, f3, h1);
        *(uint4*)((char*)sX + oA0) = h0;
        *(uint4*)((char*)sX + oA1) = h1;
        __syncthreads();

        f16x8 aw[4], bx[4];
#pragma unroll
        for (int i = 0; i < 4; ++i)
            aw[i] = *(const f16x8*)((const char*)sW + swz_off(wrN + i * 16 + r15, q));
#pragma unroll
        for (int j = 0; j < 4; ++j)
            bx[j] = *(const f16x8*)((const char*)sX + swz_off(wcM + j * 16 + r15, q));
#pragma unroll
        for (int i = 0; i < 4; ++i)
#pragma unroll
            for (int j = 0; j < 4; ++j)
                acc[i][j] = __builtin_amdgcn_mfma_f32_16x16x32_f16(aw[i], bx[j], acc[i][j], 0, 0, 0);
        __syncthreads();
    }

    // C/D: row (n) = rbN + wrN + i*16 + q*4 + r; col (m) = cbM + wcM + j*16 + r15
#pragma unroll
    for (int i = 0; i < 4; ++i)
#pragma unroll
        for (int r = 0; r < 4; ++r) {
            int n = rbN + wrN + i * 16 + q * 4 + r;
            float bn = bias[n];
#pragma unroll
            for (int j = 0; j < 4; ++j) {
                int mcol = cbM + wcM + j * 16 + r15;
                float mv = (float)maskI[mcol];
                outT[(size_t)n * 32768 + mcol] = f2bf((acc[i][j][r] + bn) * mv);
            }
        }
}

// ---------------------------------------------------------------------------
// Output GEMM via fp16 MFMA (2-term, round-5 structure): f32 out = pre @ Wo + bo
// ---------------------------------------------------------------------------
__global__ __launch_bounds__(256, 2) void out_gemm_f16(
    const u16* __restrict__ A, const u16* __restrict__ BhiT,
    const u16* __restrict__ BloT, const float* __restrict__ bias,
    float* __restrict__ outp)
{
    __shared__ u16 sA[128 * 32];
    __shared__ u16 sBhi[128 * 32], sBlo[128 * 32];

    const int bid = blockIdx.x;
    const int swz = (bid & 7) * 256 + (bid >> 3);
    const int rb  = (swz >> 3) * 128;
    const int cb  = (swz & 7) * 128;
    const int t = threadIdx.x, l = t & 63, w = t >> 6;
    const int wr = (w >> 1) * 64, wc = (w & 1) * 64;

    const int rS0 = w * 32 + (l >> 2);
    const int rS1 = rS0 + 16;
    const int cS0 = (l & 3) ^ ((rS0 >> 1) & 3);
    const int cS1 = (l & 3) ^ ((rS1 >> 1) & 3);
    const u16* gA0  = A    + (size_t)(rb + rS0) * 1024 + cS0 * 8;
    const u16* gA1  = A    + (size_t)(rb + rS1) * 1024 + cS1 * 8;
    const u16* gBh0 = BhiT + (size_t)(cb + rS0) * 1024 + cS0 * 8;
    const u16* gBh1 = BhiT + (size_t)(cb + rS1) * 1024 + cS1 * 8;
    const u16* gBl0 = BloT + (size_t)(cb + rS0) * 1024 + cS0 * 8;
    const u16* gBl1 = BloT + (size_t)(cb + rS1) * 1024 + cS1 * 8;
    u16* ldsA0  = &sA[w * 1024];
    u16* ldsA1  = &sA[w * 1024 + 512];
    u16* ldsBh0 = &sBhi[w * 1024];
    u16* ldsBh1 = &sBhi[w * 1024 + 512];
    u16* ldsBl0 = &sBlo[w * 1024];
    u16* ldsBl1 = &sBlo[w * 1024 + 512];

    f32x4 acc[4][4] = {};
    const int q = l >> 4, r15 = l & 15;

    for (int k0 = 0; k0 < 1024; k0 += 32) {
        gload_lds16(gA0  + k0, ldsA0);
        gload_lds16(gA1  + k0, ldsA1);
        gload_lds16(gBh0 + k0, ldsBh0);
        gload_lds16(gBh1 + k0, ldsBh1);
        gload_lds16(gBl0 + k0, ldsBl0);
        gload_lds16(gBl1 + k0, ldsBl1);
        __syncthreads();

        f16x8 af[4], bh[4], bl[4];
#pragma unroll
        for (int i = 0; i < 4; ++i)
            af[i] = *(const f16x8*)((const char*)sA + swz_off(wr + i * 16 + r15, q));
#pragma unroll
        for (int j = 0; j < 4; ++j) {
            int off = swz_off(wc + j * 16 + r15, q);
            bh[j] = *(const f16x8*)((const char*)sBhi + off);
            bl[j] = *(const f16x8*)((const char*)sBlo + off);
        }
#pragma unroll
        for (int i = 0; i < 4; ++i)
#pragma unroll
            for (int j = 0; j < 4; ++j) {
                acc[i][j] = __builtin_amdgcn_mfma_f32_16x16x32_f16(af[i], bh[j], acc[i][j], 0, 0, 0);
                acc[i][j] = __builtin_amdgcn_mfma_f32_16x16x32_f16(af[i], bl[j], acc[i][j], 0, 0, 0);
            }
        __syncthreads();
    }

    const int col0 = cb + wc + r15;
    const int row0 = rb + wr + q * 4;
    float bv4[4];
#pragma unroll
    for (int j = 0; j < 4; ++j) bv4[j] = bias[col0 + j * 16];
#pragma unroll
    for (int i = 0; i < 4; ++i)
#pragma unroll
        for (int r = 0; r < 4; ++r) {
            int row = row0 + i * 16 + r;
#pragma unroll
            for (int j = 0; j < 4; ++j)
                outp[(size_t)row * 1024 + col0 + j * 16] = acc[i][j][r] + bv4[j];
        }
}

// ---------------------------------------------------------------------------
__global__ void mask_to_float(const int* __restrict__ mi, float* __restrict__ mo)
{
    int i = blockIdx.x * 256 + threadIdx.x;
    if (i < BN) mo[i] = (float)mi[i];
}

__global__ void sentinel_fill(float* __restrict__ o, int n)
{
    int i = blockIdx.x * 256 + threadIdx.x;
    if (i < n) o[i] = 12345.0f;
}

// ---------------------------------------------------------------------------
// avg-pool-2 along seq: q,k row-major (y 0,1); vT transposed (y 2); mask (y 3)
// ---------------------------------------------------------------------------
__global__ __launch_bounds__(256) void pool_level(
    const u16* __restrict__ qi, u16* __restrict__ qo,
    const u16* __restrict__ ki, u16* __restrict__ ko,
    const u16* __restrict__ vi, u16* __restrict__ vo,
    const float* __restrict__ mi, float* __restrict__ mo, int nRows)
{
    int idx = blockIdx.x * 256 + threadIdx.x;
    int y   = blockIdx.y;
    if (y == 3) {
        if (idx < nRows) mo[idx] = 0.5f * (mi[2 * idx] + mi[2 * idx + 1]);
        return;
    }
    if (y == 2) {
        int ns8 = nRows >> 3;
        int sh = 31 - __clz(ns8);
        int d = idx >> sh, c = idx & (ns8 - 1);
        size_t inb = (size_t)d * (nRows * 2) + c * 16;
        uint4 a = *(const uint4*)(vi + inb);
        uint4 b = *(const uint4*)(vi + inb + 8);
        float fa[8], fb[8];
        unpack8(a, fa); unpack8(b, fb);
        uint4 o;
        o.x = pack2(0.5f * (fa[0] + fa[1]), 0.5f * (fa[2] + fa[3]));
        o.y = pack2(0.5f * (fa[4] + fa[5]), 0.5f * (fa[6] + fa[7]));
        o.z = pack2(0.5f * (fb[0] + fb[1]), 0.5f * (fb[2] + fb[3]));
        o.w = pack2(0.5f * (fb[4] + fb[5]), 0.5f * (fb[6] + fb[7]));
        *(uint4*)(vo + (size_t)d * nRows + c * 8) = o;
        return;
    }
    const u16* in  = (y == 0) ? qi : ki;
    u16*       out = (y == 0) ? qo : ko;
    int r = idx >> 7, c8 = idx & 127;
    uint4 a = *(const uint4*)(in + (size_t)(2 * r) * 1024 + c8 * 8);
    uint4 b = *(const uint4*)(in + (size_t)(2 * r + 1) * 1024 + c8 * 8);
    float fa[8], fb[8];
    unpack8(a, fa); unpack8(b, fb);
    uint4 o;
    o.x = pack2(0.5f * (fa[0] + fb[0]), 0.5f * (fa[1] + fb[1]));
    o.y = pack2(0.5f * (fa[2] + fb[2]), 0.5f * (fa[3] + fb[3]));
    o.z = pack2(0.5f * (fa[4] + fb[4]), 0.5f * (fa[5] + fb[5]));
    o.w = pack2(0.5f * (fa[6] + fb[6]), 0.5f * (fa[7] + fb[7]));
    *(uint4*)(out + (size_t)r * 1024 + c8 * 8) = o;
}

// ===========================================================================
// MFMA attention level, staging via global_load_lds (source-side swizzle,
// clamped window indices; OOB contributions are zeroed by mw/inv masks, so
// output is bit-identical to the zero-padded path). WRITE_MODE:
//   0 = pyramid: write num/den at LEVEL resolution (no RMW)
//   1 = legacy:  accumulate into full-res num/den with repeat 2^lvl
// ===========================================================================
template <int WRITE_MODE>
__device__ __forceinline__ void attn_level_body(
    const u16* __restrict__ qg, const u16* __restrict__ kg,
    const u16* __restrict__ vTg, const float* __restrict__ m,
    const float* __restrict__ rpbL,
    float* __restrict__ num, float* __restrict__ den, int nl, int lvl)
{
    __shared__ u16 qs[32 * 64];
    __shared__ u16 ks_w2[2 * 32 * 104];
    __shared__ u16 vTs[64 * 96];
    __shared__ float rps[128];
    __shared__ float mwS[96];
    __shared__ float denS[64];

    const int t   = threadIdx.x;
    const int blk = blockIdx.x, h = blockIdx.y, b = blockIdx.z;
    const size_t baseRow = (size_t)b * nl + blk * 32;
    const int wbase = blk * 32 - 32;
    const int vStr = Bc * nl;
    const int w = t >> 6;

    // ---- stage q: 4KB = 1 gload_lds per wave; LDS slot l -> (row, phys chunk);
    //      source fetches LOGICAL chunk cp ^ (row&7) so LDS holds swizzled layout.
    {
        int r  = t >> 3;              // wave*8 + (lane>>3)
        int cp = t & 7;
        int cl = cp ^ (r & 7);
        gload_lds16(qg + (baseRow + r) * 1024 + h * 64 + cl * 8, &qs[w * 512]);
    }
    // ---- stage k window: 96 rows, 12 instr (3/wave); rows clamped into [0,nl) ----
#pragma unroll
    for (int it = 0; it < 3; ++it) {
        int ii = w * 3 + it;          // 0..11
        int r  = ii * 8 + ((t & 63) >> 3);
        int cp = t & 7;
        int cl = cp ^ (r & 7);
        int wp = wbase + r;
        wp = (wp < 0) ? 0 : ((wp >= nl) ? nl - 1 : wp);
        gload_lds16(kg + ((size_t)b * nl + wp) * 1024 + h * 64 + cl * 8,
                    &ks_w2[ii * 512]);
    }
    // ---- stage vT window: 64 dims x 96 seq = 768 chunks, 12 instr; chunks clamped ----
#pragma unroll
    for (int it = 0; it < 3; ++it) {
        int ii = w * 3 + it;
        int f  = ii * 64 + (t & 63);  // 0..767
        int d  = f / 12, ch = f - d * 12;
        int wp8 = wbase + ch * 8;
        wp8 = (wp8 < 0) ? 0 : ((wp8 > nl - 8) ? nl - 8 : wp8);
        gload_lds16(vTg + (size_t)(h * 64 + d) * vStr + (size_t)b * nl + wp8,
                    &vTs[ii * 512]);
    }
    if (t < 96) {
        int wp = wbase + t;
        mwS[t] = (wp >= 0 && wp < nl) ? m[b * nl + wp] : 0.f;
    }
    if (t < 127) rps[t] = rpbL[h * 127 + t];
    __syncthreads();

    const int l  = t & 63;
    const int fr = l & 15, fg = l >> 4;
    const int mi  = w >> 1;
    const int njb = (w & 1) * 3;

    f32x4 lg[3] = {};
    {
        bf16x8 aq[2];
#pragma unroll
        for (int ks = 0; ks < 2; ++ks) {
            int row = mi * 16 + fr;
            aq[ks] = *(const bf16x8*)&qs[row * 64 + (((ks * 4 + fg) ^ (row & 7)) * 8)];
        }
#pragma unroll
        for (int nj = 0; nj < 3; ++nj) {
            int row = (njb + nj) * 16 + fr;
#pragma unroll
            for (int ks = 0; ks < 2; ++ks) {
                bf16x8 bk = *(const bf16x8*)&ks_w2[row * 64 + (((ks * 4 + fg) ^ (row & 7)) * 8)];
                lg[nj] = __builtin_amdgcn_mfma_f32_16x16x32_bf16(aq[ks], bk, lg[nj], 0, 0, 0);
            }
        }
    }
    __syncthreads();

    float sum_r[4] = {0.f, 0.f, 0.f, 0.f};
#pragma unroll
    for (int nj = 0; nj < 3; ++nj) {
        int j = (njb + nj) * 16 + fr;
        float mj = mwS[j];
#pragma unroll
        for (int r = 0; r < 4; ++r) {
            int i = mi * 16 + fg * 4 + r;
            float wv = __expf(lg[nj][r] + rps[j - i + 31]) * mj;
            if (lvl > 0) {
                int bj = j >> 5, pl = j & 31;
                bool inv = (bj == 1) ||
                           (bj == 0 && i < 16 && pl >= 16) ||
                           (bj == 2 && i >= 16 && pl < 16);
                if (inv) wv = 0.f;
            }
            sum_r[r] += wv;
            u32 uw = __float_as_uint(wv);
            float lo = wv - __uint_as_float(uw & 0xffff0000u);
            ks_w2[i * 104 + j]        = (u16)(uw >> 16);
            ks_w2[3328 + i * 104 + j] = (u16)(__float_as_uint(lo) >> 16);
        }
    }
#pragma unroll
    for (int r = 0; r < 4; ++r) {
        sum_r[r] += __shfl_xor(sum_r[r], 1);
        sum_r[r] += __shfl_xor(sum_r[r], 2);
        sum_r[r] += __shfl_xor(sum_r[r], 4);
        sum_r[r] += __shfl_xor(sum_r[r], 8);
    }
    if (fr == 0) {
#pragma unroll
        for (int r = 0; r < 4; ++r)
            denS[(w & 1) * 32 + mi * 16 + fg * 4 + r] = sum_r[r];
    }
    __syncthreads();

    const int ndb = (w & 1) * 2;
    f32x4 acc0 = {}, acc1 = {};
#pragma unroll
    for (int ks = 0; ks < 3; ++ks) {
        int arow = mi * 16 + fr;
        bf16x8 ah = *(const bf16x8*)&ks_w2[arow * 104 + ks * 32 + fg * 8];
        bf16x8 al = *(const bf16x8*)&ks_w2[3328 + arow * 104 + ks * 32 + fg * 8];
        int d0 = ndb * 16 + fr;
        bf16x8 bv0 = *(const bf16x8*)&vTs[d0 * 96 + ks * 32 + fg * 8];
        bf16x8 bv1 = *(const bf16x8*)&vTs[(d0 + 16) * 96 + ks * 32 + fg * 8];
        acc0 = __builtin_amdgcn_mfma_f32_16x16x32_bf16(ah, bv0, acc0, 0, 0, 0);
        acc0 = __builtin_amdgcn_mfma_f32_16x16x32_bf16(al, bv0, acc0, 0, 0, 0);
        acc1 = __builtin_amdgcn_mfma_f32_16x16x32_bf16(ah, bv1, acc1, 0, 0, 0);
        acc1 = __builtin_amdgcn_mfma_f32_16x16x32_bf16(al, bv1, acc1, 0, 0, 0);
    }

    const int i0 = mi * 16 + fg * 4;
    const int d0 = ndb * 16 + fr;
    if (WRITE_MODE == 0) {
#pragma unroll
        for (int r = 0; r < 4; ++r) {
            int cn = blk * 32 + i0 + r;
            size_t base = ((size_t)b * nl + cn) * 1024 + h * 64;
            num[base + d0]      = acc0[r];
            num[base + d0 + 16] = acc1[r];
        }
        if (t < 32) {
            float s = denS[t] + denS[32 + t];
            den[((size_t)b * nl + blk * 32 + t) * 16 + h] = s;
        }
    } else {
        const int rr = 1 << lvl;
#pragma unroll
        for (int r = 0; r < 4; ++r) {
            int cn = blk * 32 + i0 + r;
            size_t base = ((size_t)b * Nc + (size_t)cn * rr) * 1024 + h * 64;
            if (lvl == 0) {
                num[base + d0]      = acc0[r];
                num[base + d0 + 16] = acc1[r];
            } else {
                for (int rep = 0; rep < rr; ++rep) {
                    num[base + (size_t)rep * 1024 + d0]      += acc0[r];
                    num[base + (size_t)rep * 1024 + d0 + 16] += acc1[r];
                }
            }
        }
        if (t < 32) {
            float s = denS[t] + denS[32 + t];
            int cn = blk * 32 + t;
            size_t db = ((size_t)b * Nc + (size_t)cn * rr) * 16 + h;
            if (lvl == 0) {
                den[db] = s;
            } else {
                for (int rep = 0; rep < rr; ++rep) den[db + (size_t)rep * 16] += s;
            }
        }
    }
}

__global__ __launch_bounds__(256) void attn_level_pyr(
    const u16* __restrict__ qg, const u16* __restrict__ kg,
    const u16* __restrict__ vTg, const float* __restrict__ m,
    const float* __restrict__ rpbL,
    float* __restrict__ numL, float* __restrict__ denL, int nl, int lvl)
{
    attn_level_body<0>(qg, kg, vTg, m, rpbL, numL, denL, nl, lvl);
}

__global__ __launch_bounds__(256) void attn_level_rmw(
    const u16* __restrict__ qg, const u16* __restrict__ kg,
    const u16* __restrict__ vTg, const float* __restrict__ m,
    const float* __restrict__ rpbL,
    float* __restrict__ num, float* __restrict__ den, int nl, int lvl)
{
    attn_level_body<1>(qg, kg, vTg, m, rpbL, num, den, nl, lvl);
}

// ---------------------------------------------------------------------------
// combine (legacy): pre_fp16 = num / (den + 1e-9) * qmask
// ---------------------------------------------------------------------------
__global__ __launch_bounds__(256) void combine_kernel(
    const float* __restrict__ num, const float* __restrict__ den,
    const int* __restrict__ qmask, u16* __restrict__ pre)
{
    int idx = blockIdx.x * 256 + threadIdx.x;
    int row = idx >> 8, c4 = idx & 255;
    int h = c4 >> 4;
    float4 ns = *(const float4*)&num[(size_t)row * 1024 + c4 * 4];
    float f = (float)qmask[row] / (den[(size_t)row * 16 + h] + 1e-9f);
    ushort4 o;
    o.x = f2h(ns.x * f); o.y = f2h(ns.y * f);
    o.z = f2h(ns.z * f); o.w = f2h(ns.w * f);
    *(ushort4*)(pre + (size_t)row * 1024 + c4 * 4) = o;
}

// ---------------------------------------------------------------------------
// combine (pyramid): gather 8 levels, sum f32 in level order; pre as fp16.
// ---------------------------------------------------------------------------
__global__ __launch_bounds__(256) void combine_pyr(
    P8 nums, P8 dens, const int* __restrict__ qmask, u16* __restrict__ pre)
{
    int idx = blockIdx.x * 256 + threadIdx.x;
    int row = idx >> 8, c4 = idx & 255;
    int h = c4 >> 4;
    int b = row >> 13, s = row & (Nc - 1);
    float4 acc = make_float4(0.f, 0.f, 0.f, 0.f);
    float dt = 0.f;
#pragma unroll
    for (int l = 0; l < 8; ++l) {
        int rl = (b << (13 - l)) + (s >> l);
        const float4 nv = *(const float4*)&nums.p[l][(size_t)rl * 1024 + c4 * 4];
        acc.x += nv.x; acc.y += nv.y; acc.z += nv.z; acc.w += nv.w;
        dt += dens.p[l][(size_t)rl * 16 + h];
    }
    float f = (float)qmask[row] / (dt + 1e-9f);
    ushort4 o;
    o.x = f2h(acc.x * f); o.y = f2h(acc.y * f);
    o.z = f2h(acc.z * f); o.w = f2h(acc.w * f);
    *(ushort4*)(pre + (size_t)row * 1024 + c4 * 4) = o;
}

// ---------------------------------------------------------------------------
extern "C" void kernel_launch(void* const* d_in, const int* in_sizes, int n_in,
                              void* d_out, int out_size, void* d_ws, size_t ws_size,
                              hipStream_t stream)
{
    const float* Xq    = (const float*)d_in[0];
    const float* Xkv   = (const float*)d_in[1];
    const int*   qmask = (const int*)d_in[2];
    const int*   kmask = (const int*)d_in[3];
    const float* Wq    = (const float*)d_in[4];
    const float* bq    = (const float*)d_in[5];
    const float* Wk    = (const float*)d_in[6];
    const float* bk    = (const float*)d_in[7];
    const float* Wv    = (const float*)d_in[8];
    const float* bv    = (const float*)d_in[9];
    const float* Wo    = (const float*)d_in[10];
    const float* bo    = (const float*)d_in[11];
    const float* rpb   = (const float*)d_in[12];

    const size_t szA = (size_t)BN * HD * 2;   // 67,108,864
    const size_t szB = szA / 2;
    const size_t base_need = 3 * (szA + szB) + (size_t)BN * 6;

    size_t denPyrSz = 0, numPyrSz = 0;
    for (int l = 0; l < 8; ++l) denPyrSz += ((size_t)(BN >> l)) * 16 * 4;
    for (int l = 1; l < 8; ++l) numPyrSz += ((size_t)(BN >> l)) * 1024 * 4;
    const size_t needed_old = base_need + (size_t)BN * 16 * 4;
    const size_t needed_pyr = base_need + denPyrSz + numPyrSz;

    const bool usePyr = (ws_size >= needed_pyr);
    if (!usePyr && ws_size < needed_old) {
        sentinel_fill<<<(out_size + 255) / 256, 256, 0, stream>>>((float*)d_out, out_size);
        return;
    }

    char* p = (char*)d_ws;
    u16* qA = (u16*)p; p += szA;
    u16* qB = (u16*)p; p += szB;
    u16* kA = (u16*)p; p += szA;
    u16* kB = (u16*)p; p += szB;
    u16* vA = (u16*)p; p += szA;     // vT pyramid (transposed)
    u16* vB = (u16*)p; p += szB;
    float* mA  = (float*)p; p += (size_t)BN * 4;
    float* mB  = (float*)p; p += (size_t)BN * 2;

    P8 numP, denP;
    float* denLegacy = nullptr;
    if (usePyr) {
        for (int l = 0; l < 8; ++l) { denP.p[l] = (float*)p; p += ((size_t)(BN >> l)) * 16 * 4; }
        numP.p[0] = (float*)d_out;
        for (int l = 1; l < 8; ++l) { numP.p[l] = (float*)p; p += ((size_t)(BN >> l)) * 1024 * 4; }
    } else {
        denLegacy = (float*)p;
    }
    float* num = (float*)d_out;

    u16* WsHi0 = qB;
    u16* WsLo0 = qB + 1 * 1048576;
    u16* WsHi1 = qB + 2 * 1048576;
    u16* WsHi2 = qB + 4 * 1048576;

    dim3 tsg(32, 32);
    transpose_split_f16<<<tsg, 256, 0, stream>>>(Wq, WsHi0, nullptr);
    transpose_split_f16<<<tsg, 256, 0, stream>>>(Wk, WsHi1, nullptr);
    transpose_split_f16<<<tsg, 256, 0, stream>>>(Wv, WsHi2, nullptr);

    proj_gemm_f16 <<<2048, 256, 0, stream>>>(Xq,  WsHi0, bq, nullptr, qA, 0.125f);
    proj_gemm_f16 <<<2048, 256, 0, stream>>>(Xkv, WsHi1, bk, nullptr, kA, 1.f);
    vproj_gemm_T_f16<<<2048, 256, 0, stream>>>(Xkv, WsHi2, bv, kmask, vA);
    mask_to_float<<<BN / 256, 256, 0, stream>>>(kmask, mA);

    u16* qc = qA; u16* kc = kA; u16* vc = vA; float* mc = mA;
    u16* qn = qB; u16* kn = kB; u16* vn = vB; float* mn = mB;
    for (int lvl = 0; lvl < 8; ++lvl) {
        int nl = Nc >> lvl, nb = nl / 32;
        if (usePyr) {
            attn_level_pyr<<<dim3(nb, 16, 4), 256, 0, stream>>>(
                qc, kc, vc, mc, rpb + (size_t)lvl * Hc * 127,
                numP.p[lvl], denP.p[lvl], nl, lvl);
        } else {
            attn_level_rmw<<<dim3(nb, 16, 4), 256, 0, stream>>>(
                qc, kc, vc, mc, rpb + (size_t)lvl * Hc * 127,
                num, denLegacy, nl, lvl);
        }
        if (lvl < 7) {
            int nRows = Bc * (nl / 2);
            pool_level<<<dim3(nRows / 2, 4), 256, 0, stream>>>(
                qc, qn, kc, kn, vc, vn, mc, mn, nRows);
            u16* tp;
            tp = qc; qc = qn; qn = tp;
            tp = kc; kc = kn; kn = tp;
            tp = vc; vc = vn; vn = tp;
            float* tf = mc; mc = mn; mn = tf;
        }
    }

    if (usePyr) {
        combine_pyr<<<BN, 256, 0, stream>>>(numP, denP, qmask, qA);
    } else {
        combine_kernel<<<BN, 256, 0, stream>>>(num, denLegacy, qmask, qA);
    }
    // Wo hi/lo fp16 split into qB (dead after last pool; slots 0 and 1)
    u16* WoHi = qB;
    u16* WoLo = qB + 1 * 1048576;
    transpose_split_f16<<<tsg, 256, 0, stream>>>(Wo, WoHi, WoLo);
    out_gemm_f16<<<2048, 256, 0, stream>>>(qA, WoHi, WoLo, bo, (float*)d_out);
}